// Round 12
// baseline (995.231 us; speedup 1.0000x reference)
//
#include <hip/hip_runtime.h>

#define EPSV  1e-20f
#define BNEPS 1e-5f

typedef _Float16 f16x8 __attribute__((ext_vector_type(8)));
typedef _Float16 f16x4 __attribute__((ext_vector_type(4)));
typedef float    f32x4 __attribute__((ext_vector_type(4)));

__device__ inline unsigned pack2f16(float a, float b) {
    unsigned short ua = __builtin_bit_cast(unsigned short, (_Float16)a);
    unsigned short ub = __builtin_bit_cast(unsigned short, (_Float16)b);
    return ((unsigned)ub << 16) | ua;
}

// ---------------------------------------------------------------------------
// prep_generic: wn = |w|/(sum+eps), chunked GEMM layouts (blocks 1/2):
//   wBh[kc(ci/32)][tap ][co(COUT)][ci%32]
//   wAh[kc(co/32)][tapf][ci(CIN) ][co%32]
// ---------------------------------------------------------------------------
__device__ __forceinline__ void prep_generic(const float* __restrict__ w, int CIN, int COUT,
                                             _Float16* __restrict__ wAh, _Float16* __restrict__ wBh,
                                             int co, int tid, float* red)
{
    const int N = CIN * 9;
    const float* wrow = w + (size_t)co * N;
    float s = 0.f;
    for (int i = tid; i < N; i += 256) s += fabsf(wrow[i]);
    #pragma unroll
    for (int m = 32; m; m >>= 1) s += __shfl_xor(s, m, 64);
    if ((tid & 63) == 0) red[tid >> 6] = s;
    __syncthreads();
    s = red[0] + red[1] + red[2] + red[3];
    const float rn = 1.f / (s + EPSV);
    for (int i = tid; i < N; i += 256) {
        const int ci = i / 9, tap = i % 9;
        const int ky = tap / 3, kx = tap % 3;
        const float v = fabsf(wrow[i]) * rn;
        const int tf = (2 - ky) * 3 + (2 - kx);
        wBh[(((size_t)(ci >> 5) * 9 + tap) * COUT + co) * 32 + (ci & 31)] = (_Float16)v;
        wAh[(((size_t)(co >> 5) * 9 + tf) * CIN + ci) * 32 + (co & 31)] = (_Float16)v;
    }
}

// All weight prep in one launch. Sections by blockIdx.x:
//  [0,64): block0 (CIN=3): wA0h[kc][tf][16ci][32co], wB0h[tap][64co][32ci]
//  [64,192): block1; [192,448): block2; [448,464): w1h0; [464,528): w1h1; [528,784): w1h2
__global__ __launch_bounds__(256) void prep_all_kernel(
    const float* __restrict__ w0,  const float* __restrict__ w1_0,
    const float* __restrict__ wb1, const float* __restrict__ w1_1,
    const float* __restrict__ wb2, const float* __restrict__ w1_2,
    _Float16* __restrict__ wA0h, _Float16* __restrict__ wB0h,
    _Float16* __restrict__ wA1h, _Float16* __restrict__ wB1h,
    _Float16* __restrict__ wA2h, _Float16* __restrict__ wB2h,
    _Float16* __restrict__ w1h0, _Float16* __restrict__ w1h1, _Float16* __restrict__ w1h2)
{
    __shared__ float red[4];
    const int bid = blockIdx.x, tid = threadIdx.x;
    if (bid < 64) {
        const int co = bid;
        float s = (tid < 27) ? fabsf(w0[co * 27 + tid]) : 0.f;
        #pragma unroll
        for (int m = 32; m; m >>= 1) s += __shfl_xor(s, m, 64);
        if ((tid & 63) == 0) red[tid >> 6] = s;
        __syncthreads();
        s = red[0] + red[1] + red[2] + red[3];
        const float rn = 1.f / (s + EPSV);
        for (int i = tid; i < 9 * 32; i += 256) {
            const int tap = i / 32, ci = i % 32;
            const float v = (ci < 3) ? fabsf(w0[co * 27 + ci * 9 + tap]) * rn : 0.f;
            wB0h[((size_t)tap * 64 + co) * 32 + ci] = (_Float16)v;
        }
        for (int i = tid; i < 9 * 16; i += 256) {
            const int tf = i / 16, ci = i % 16;
            float v = 0.f;
            if (ci < 3) {
                const int tap = (2 - tf / 3) * 3 + (2 - tf % 3);
                v = fabsf(w0[co * 27 + ci * 9 + tap]) * rn;
            }
            wA0h[((((size_t)(co >> 5) * 9 + tf) * 16 + ci) * 32) + (co & 31)] = (_Float16)v;
        }
    } else if (bid < 192) {
        prep_generic(wb1, 64, 128, wA1h, wB1h, bid - 64, tid, red);
    } else if (bid < 448) {
        prep_generic(wb2, 128, 256, wA2h, wB2h, bid - 192, tid, red);
    } else if (bid < 464) {
        const int i = (bid - 448) * 256 + tid; w1h0[i] = (_Float16)w1_0[i];
    } else if (bid < 528) {
        const int i = (bid - 464) * 256 + tid; w1h1[i] = (_Float16)w1_1[i];
    } else {
        const int i = (bid - 528) * 256 + tid; w1h2[i] = (_Float16)w1_2[i];
    }
}

// ---------------------------------------------------------------------------
// xn prep (block0): x NCHW fp32 -> xn [pix][4] f16 (ch3=0).
// ---------------------------------------------------------------------------
__global__ __launch_bounds__(256) void xn0_kernel(const float* __restrict__ x,
                                                  _Float16* __restrict__ xn4,
                                                  int npx, int HW)
{
    const int p = blockIdx.x * 256 + threadIdx.x;
    if (p >= npx) return;
    const int b = p / HW, r = p % HW;
    const float* ip = x + (size_t)b * 3 * HW + r;
    const float v0 = fmaxf(ip[0], 0.f), v1 = fmaxf(ip[HW], 0.f), v2 = fmaxf(ip[2 * HW], 0.f);
    const float rs = 1.f / (v0 + v1 + v2 + EPSV);
    unsigned* d = (unsigned*)(xn4 + (size_t)p * 4);
    d[0] = pack2f16(v0 * rs, v1 * rs);
    d[1] = pack2f16(v2 * rs, 0.f);
}

// ---------------------------------------------------------------------------
// mffuse: ONE kernel = full NNMF iteration for a 16x16 tile (blocks 0/1).
//  Phase A: ratio = xn / conv_A(h/S) on the 18x18 halo region, kept in LDS.
//  Phase B: h = (FIRST ? 1 : h) * conv_B(ratio) RMW + per-pixel S.
//  Weight pieces ping-pong through the dead phase-A LDS regions.
// ---------------------------------------------------------------------------
template<int COUT, int CINP, int NFA, int NPO, int XST, int XNC, bool FIRST>
__global__ __launch_bounds__(256, 1) void mffuse_kernel(
    _Float16* __restrict__ h, const _Float16* __restrict__ wA,
    const _Float16* __restrict__ wB, const _Float16* __restrict__ xn,
    float* __restrict__ S, int H, int W)
{
    constexpr int OCA  = NFA * 16;
    constexpr int NCHA = COUT / 32;
    constexpr int NCHB = CINP / 32;
    constexpr int OCP  = COUT / NPO;
    constexpr int NFB  = OCP / 16;
    constexpr int NPIECES = NPO * NCHB;
    constexpr int ICPH = 40;
    constexpr int NSPA = 400;
    constexpr int ICP2 = CINP + 8;
    constexpr int NRPX = 324;
    constexpr int PIECE = 9 * OCP * 32;
    constexpr int WRS0  = 9 * OCA * 32;
    constexpr int IRS = (16000 > PIECE) ? 16000 : PIECE;
    constexpr int WRS = (NPIECES > 1 && PIECE > WRS0) ? PIECE : WRS0;
    constexpr int NLDA = NSPA * 4;
    constexpr int IREGA = (NLDA + 255) / 256;
    constexpr int NWLA = 9 * OCA * 4;
    constexpr int WREGA = (NWLA + 255) / 256;
    constexpr int NWLB = PIECE / 8;
    constexpr int WREGB = (NWLB + 255) / 256;

    __shared__ float rS_s[NSPA];
    __shared__ _Float16 lds_I[IRS];
    __shared__ _Float16 lds_W[WRS];
    __shared__ _Float16 lds_R[NRPX * ICP2];

    const int tid = threadIdx.x;
    const int lane = tid & 63, wave = tid >> 6;
    const int kq = lane >> 4, l15 = lane & 15;
    const int x0 = blockIdx.x * 16, y0 = blockIdx.y * 16, b = blockIdx.z;
    const int HW = H * W;

    f16x8 ild[IREGA];
    f16x8 wla[WREGA];
    f16x8 wlb[WREGB];

    auto iloadA = [&](int kc) {
        #pragma unroll
        for (int r = 0; r < IREGA; ++r) {
            const int i = tid + r * 256;
            f16x8 v = {0, 0, 0, 0, 0, 0, 0, 0};
            if (i < NLDA) {
                const int sp = i >> 2, seg = i & 3;
                const int yy = y0 + sp / 20 - 2, xx = x0 + sp % 20 - 2;
                if (yy >= 0 && yy < H && xx >= 0 && xx < W)
                    v = __builtin_nontemporal_load((const f16x8*)(h +
                        ((size_t)b * HW + (size_t)yy * W + xx) * COUT + kc * 32 + seg * 8));
            }
            ild[r] = v;
        }
    };
    auto iwriteA = [&]() {
        #pragma unroll
        for (int r = 0; r < IREGA; ++r) {
            const int i = tid + r * 256;
            if (i < NLDA) {
                const int sp = i >> 2, seg = i & 3;
                const float f = rS_s[sp];
                unsigned* d = (unsigned*)&lds_I[sp * ICPH + seg * 8];
                d[0] = pack2f16((float)ild[r][0] * f, (float)ild[r][1] * f);
                d[1] = pack2f16((float)ild[r][2] * f, (float)ild[r][3] * f);
                d[2] = pack2f16((float)ild[r][4] * f, (float)ild[r][5] * f);
                d[3] = pack2f16((float)ild[r][6] * f, (float)ild[r][7] * f);
            }
        }
    };
    auto wloadA = [&](int kc) {
        #pragma unroll
        for (int r = 0; r < WREGA; ++r) {
            const int j = tid + r * 256;
            if (j < NWLA) {
                const int tap = j / (OCA * 4), rem = j % (OCA * 4);
                const int oc = rem >> 2, e = rem & 3;
                wla[r] = *(const f16x8*)(wA + (((size_t)kc * 9 + tap) * OCA + oc) * 32 + e * 8);
            }
        }
    };
    auto wwriteA = [&]() {
        #pragma unroll
        for (int r = 0; r < WREGA; ++r) {
            const int j = tid + r * 256;
            if (j < NWLA) {
                const int tap = j / (OCA * 4), rem = j % (OCA * 4);
                const int oc = rem >> 2, e = rem & 3;
                const int slot = e ^ ((oc >> 1) & 3);
                *(f16x8*)&lds_W[tap * (OCA * 32) + oc * 32 + slot * 8] = wla[r];
            }
        }
    };
    auto wloadB = [&](int p) {
        const int oh = p / NCHB, kc = p % NCHB;
        #pragma unroll
        for (int r = 0; r < WREGB; ++r) {
            const int j = tid + r * 256;
            if (j < NWLB) {
                const int tap = j / (OCP * 4), rem = j % (OCP * 4);
                const int oc = rem >> 2, e = rem & 3;
                wlb[r] = *(const f16x8*)(wB +
                    (((size_t)kc * 9 + tap) * COUT + oh * OCP + oc) * 32 + e * 8);
            }
        }
    };
    auto wwriteB = [&](int p) {
        _Float16* dst = (p & 1) ? lds_W : lds_I;
        #pragma unroll
        for (int r = 0; r < WREGB; ++r) {
            const int j = tid + r * 256;
            if (j < NWLB) {
                const int tap = j / (OCP * 4), rem = j % (OCP * 4);
                const int oc = rem >> 2, e = rem & 3;
                const int slot = e ^ ((oc >> 1) & 3);
                *(f16x8*)&dst[tap * (OCP * 32) + oc * 32 + slot * 8] = wlb[r];
            }
        }
    };

    int ryj[6], rxj[6];
    bool vj[6];
    #pragma unroll
    for (int j = 0; j < 6; ++j) {
        const int f = wave + 4 * j;
        vj[j] = (f < 21);
        const int p = f * 16 + l15;
        const int pc = (p < NRPX) ? p : (NRPX - 1);
        ryj[j] = pc / 18; rxj[j] = pc % 18;
    }

    f32x4 racc[6][NFA];
    #pragma unroll
    for (int j = 0; j < 6; ++j)
        #pragma unroll
        for (int nfa = 0; nfa < NFA; ++nfa) racc[j][nfa] = (f32x4){0.f, 0.f, 0.f, 0.f};

    // ---- prologue ----
    if constexpr (!FIRST) iloadA(0);
    wloadA(0);
    if constexpr (XNC < CINP) {
        for (int i = tid; i < NRPX * ICP2 / 2; i += 256) ((unsigned*)lds_R)[i] = 0u;
    }
    if constexpr (!FIRST) {
        for (int i = tid; i < NSPA; i += 256) {
            const int yy = y0 + i / 20 - 2, xx = x0 + i % 20 - 2;
            float sv = 0.f;
            if (yy >= 0 && yy < H && xx >= 0 && xx < W)
                sv = S[(size_t)b * HW + (size_t)yy * W + xx];
            rS_s[i] = 1.f / (sv + EPSV);
        }
        __syncthreads();
        iwriteA();
    } else {
        const unsigned cpk = pack2f16(1.f / (float)COUT, 1.f / (float)COUT);
        for (int i = tid; i < NSPA; i += 256) {
            const int yy = y0 + i / 20 - 2, xx = x0 + i % 20 - 2;
            const bool ok = (yy >= 0 && yy < H && xx >= 0 && xx < W);
            unsigned* d = (unsigned*)&lds_I[i * ICPH];
            #pragma unroll
            for (int sg = 0; sg < 16; ++sg) d[sg] = ok ? cpk : 0u;
        }
    }
    wwriteA();
    __syncthreads();

    // ---- phase A ----
    for (int kc = 0; kc < NCHA; ++kc) {
        if (kc + 1 < NCHA) {
            if constexpr (!FIRST) iloadA(kc + 1);
            wloadA(kc + 1);
        }
        #pragma unroll
        for (int tap = 0; tap < 9; ++tap) {
            const int dy = tap / 3, dx = tap % 3;
            f16x8 bfr[NFA];
            #pragma unroll
            for (int nfa = 0; nfa < NFA; ++nfa) {
                const int oc = nfa * 16 + l15;
                bfr[nfa] = *(const f16x8*)&lds_W[tap * (OCA * 32) + oc * 32 + (kq ^ ((oc >> 1) & 3)) * 8];
            }
            #pragma unroll
            for (int j = 0; j < 6; ++j) {
                if (vj[j]) {
                    const f16x8 afr = *(const f16x8*)&lds_I[((ryj[j] + dy) * 20 + rxj[j] + dx) * ICPH + kq * 8];
                    #pragma unroll
                    for (int nfa = 0; nfa < NFA; ++nfa)
                        racc[j][nfa] = __builtin_amdgcn_mfma_f32_16x16x32_f16(afr, bfr[nfa], racc[j][nfa], 0, 0, 0);
                }
            }
        }
        if (kc + 1 < NCHA) {
            __syncthreads();
            if constexpr (!FIRST) iwriteA();
            wwriteA();
            __syncthreads();
        }
    }

    // ---- phase A epilogue: ratio -> lds_R ----
    wloadB(0);
    #pragma unroll
    for (int j = 0; j < 6; ++j) {
        if (!vj[j]) continue;
        const int f = wave + 4 * j;
        #pragma unroll
        for (int r = 0; r < 4; ++r) {
            const int p = f * 16 + kq * 4 + r;
            if (p < NRPX) {
                const int ry = p / 18, rx = p % 18;
                const int gy = y0 - 1 + ry, gx = x0 - 1 + rx;
                const bool ok = (gy >= 0 && gy < H && gx >= 0 && gx < W);
                #pragma unroll
                for (int nfa = 0; nfa < NFA; ++nfa) {
                    const int oc = nfa * 16 + l15;
                    float rv = 0.f;
                    if (ok && oc < XNC) {
                        const size_t pb = (size_t)b * HW + (size_t)gy * W + gx;
                        rv = (float)xn[pb * XST + oc] / (racc[j][nfa][r] + EPSV);
                    }
                    lds_R[p * ICP2 + oc] = (_Float16)rv;
                }
            }
        }
    }
    __syncthreads();
    wwriteB(0);
    __syncthreads();

    // ---- phase B ----
    const int prow = wave * 4;
    float ssum[4][4];
    #pragma unroll
    for (int mf = 0; mf < 4; ++mf)
        #pragma unroll
        for (int r = 0; r < 4; ++r) ssum[mf][r] = 0.f;

    for (int oh = 0; oh < NPO; ++oh) {
        f32x4 uacc[4][NFB];
        #pragma unroll
        for (int mf = 0; mf < 4; ++mf)
            #pragma unroll
            for (int nfb = 0; nfb < NFB; ++nfb) uacc[mf][nfb] = (f32x4){0.f, 0.f, 0.f, 0.f};

        for (int kc = 0; kc < NCHB; ++kc) {
            const int p = oh * NCHB + kc;
            if (p + 1 < NPIECES) wloadB(p + 1);
            const _Float16* wpb = (p & 1) ? lds_W : lds_I;
            #pragma unroll
            for (int tap = 0; tap < 9; ++tap) {
                const int dy = tap / 3, dx = tap % 3;
                f16x8 bfr[NFB];
                #pragma unroll
                for (int nfb = 0; nfb < NFB; ++nfb) {
                    const int oc = nfb * 16 + l15;
                    bfr[nfb] = *(const f16x8*)&wpb[tap * (OCP * 32) + oc * 32 + (kq ^ ((oc >> 1) & 3)) * 8];
                }
                #pragma unroll
                for (int mf = 0; mf < 4; ++mf) {
                    const f16x8 afr = *(const f16x8*)&lds_R[((prow + mf + dy) * 18 + l15 + dx) * ICP2 + kc * 32 + kq * 8];
                    #pragma unroll
                    for (int nfb = 0; nfb < NFB; ++nfb)
                        uacc[mf][nfb] = __builtin_amdgcn_mfma_f32_16x16x32_f16(afr, bfr[nfb], uacc[mf][nfb], 0, 0, 0);
                }
            }
            if (p + 1 < NPIECES) {
                __syncthreads();
                wwriteB(p + 1);
                __syncthreads();
            }
        }
        #pragma unroll
        for (int mf = 0; mf < 4; ++mf) {
            const int gy = y0 + prow + mf;
            const size_t pixbase = (size_t)b * HW + (size_t)gy * W + x0 + kq * 4;
            #pragma unroll
            for (int nfb = 0; nfb < NFB; ++nfb) {
                const int oc = oh * OCP + nfb * 16 + l15;
                #pragma unroll
                for (int r = 0; r < 4; ++r) {
                    const size_t idx = (pixbase + r) * COUT + oc;
                    float hv;
                    if constexpr (FIRST) hv = uacc[mf][nfb][r];
                    else                 hv = (float)h[idx] * uacc[mf][nfb][r];
                    const _Float16 hq = (_Float16)hv;
                    h[idx] = hq;
                    ssum[mf][r] += (float)hq;
                }
            }
        }
    }
    #pragma unroll
    for (int mf = 0; mf < 4; ++mf) {
        #pragma unroll
        for (int r = 0; r < 4; ++r) {
            float v = ssum[mf][r];
            v += __shfl_xor(v, 1); v += __shfl_xor(v, 2);
            v += __shfl_xor(v, 4); v += __shfl_xor(v, 8);
            if (l15 == 0) {
                const int gy = y0 + prow + mf;
                S[(size_t)b * HW + (size_t)gy * W + x0 + kq * 4 + r] = v;
            }
        }
    }
}

// ---------------------------------------------------------------------------
// mfconv5 (block2 path, unchanged from R11).
// ---------------------------------------------------------------------------
template<int ICg, int OCg, int NSPLIT, int OST, int NW, int NSIN,
         bool NORM_IN, bool UPDATE, bool FIRST>
__global__ __launch_bounds__(256, 1) void mfconv5(
    const _Float16* __restrict__ in, const _Float16* __restrict__ wgt,
    const _Float16* __restrict__ aux, _Float16* __restrict__ out,
    const float* __restrict__ Sin, float* __restrict__ Sout,
    int H, int W, int sstride)
{
    constexpr bool CSTAGE = FIRST && NORM_IN;
    constexpr int OCWG = OCg / NSPLIT;
    constexpr int NF = OCWG / 16;
    constexpr int HS = 18, WSp = 18, NSP = HS * WSp;
    constexpr int ICP = 40;
    constexpr int NCH = ICg / 32;
    constexpr int LS = (NSPLIT == 4) ? 2 : (NSPLIT == 2) ? 1 : 0;
    constexpr int NLD = NSP * 4;
    constexpr int IREG = (NLD + 255) / 256;
    constexpr int WOC = OCWG * 32;
    constexpr int NWLD = 9 * OCWG * 4;
    constexpr int WREG = (NWLD + 255) / 256;
    static_assert(OCWG % 16 == 0 && ICg % 32 == 0, "cfg");

    __shared__ _Float16 in_t[CSTAGE ? 1 : 2][NSP * ICP];
    __shared__ _Float16 w_t[2][9 * WOC];
    __shared__ float rS[(NORM_IN && !FIRST) ? NSP : 1];

    const int tid = threadIdx.x;
    const int lane = tid & 63, wave = tid >> 6;
    const int kq = lane >> 4, l15 = lane & 15;
    const int split = blockIdx.x & (NSPLIT - 1);
    const int tx = blockIdx.x >> LS;
    const int x0 = tx * 16, y0 = blockIdx.y * 16, b = blockIdx.z;
    const int HW = H * W;
    const int oc0 = split * OCWG;

    f16x8 ild[CSTAGE ? 1 : IREG];
    f16x8 wld[WREG];

    auto iload = [&](int kc) {
        #pragma unroll
        for (int r = 0; r < IREG; ++r) {
            const int i = tid + r * 256;
            f16x8 v = {0, 0, 0, 0, 0, 0, 0, 0};
            if (i < NLD) {
                const int sp = i >> 2, seg = i & 3;
                const int yy = y0 + sp / WSp - 1, xx = x0 + sp % WSp - 1;
                if (yy >= 0 && yy < H && xx >= 0 && xx < W)
                    v = __builtin_nontemporal_load((const f16x8*)(in +
                        ((size_t)b * HW + (size_t)yy * W + xx) * ICg + kc * 32 + seg * 8));
            }
            ild[r] = v;
        }
    };
    auto wload = [&](int kc) {
        #pragma unroll
        for (int r = 0; r < WREG; ++r) {
            const int j = tid + r * 256;
            if (j < NWLD) {
                const int tap = j / (OCWG * 4), rem = j % (OCWG * 4);
                const int oc = rem >> 2, e = rem & 3;
                wld[r] = *(const f16x8*)(wgt +
                    (((size_t)kc * 9 + tap) * OCg + oc0 + oc) * 32 + e * 8);
            }
        }
    };
    auto iwrite = [&](int buf) {
        #pragma unroll
        for (int r = 0; r < IREG; ++r) {
            const int i = tid + r * 256;
            if (i < NLD) {
                const int sp = i >> 2, seg = i & 3;
                if constexpr (NORM_IN && !FIRST) {
                    const float f = rS[sp];
                    unsigned* d = (unsigned*)&in_t[buf][sp * ICP + seg * 8];
                    d[0] = pack2f16((float)ild[r][0] * f, (float)ild[r][1] * f);
                    d[1] = pack2f16((float)ild[r][2] * f, (float)ild[r][3] * f);
                    d[2] = pack2f16((float)ild[r][4] * f, (float)ild[r][5] * f);
                    d[3] = pack2f16((float)ild[r][6] * f, (float)ild[r][7] * f);
                } else {
                    *(f16x8*)&in_t[buf][sp * ICP + seg * 8] = ild[r];
                }
            }
        }
    };
    auto wwrite = [&](int buf) {
        #pragma unroll
        for (int r = 0; r < WREG; ++r) {
            const int j = tid + r * 256;
            if (j < NWLD) {
                const int tap = j / (OCWG * 4), rem = j % (OCWG * 4);
                const int oc = rem >> 2, e = rem & 3;
                const int slot = e ^ ((oc >> 1) & 3);
                *(f16x8*)&w_t[buf][tap * WOC + oc * 32 + slot * 8] = wld[r];
            }
        }
    };

    const int prow = wave * 4;

    f32x4 acc[4][NF];
    #pragma unroll
    for (int mf = 0; mf < 4; ++mf)
        #pragma unroll
        for (int nf = 0; nf < NF; ++nf) acc[mf][nf] = (f32x4){0.f, 0.f, 0.f, 0.f};

    if constexpr (!CSTAGE) iload(0);
    wload(0);
    if constexpr (NORM_IN && !FIRST) {
        for (int i = tid; i < NSP; i += 256) {
            const int yy = y0 + i / WSp - 1, xx = x0 + i % WSp - 1;
            float sv = 0.f;
            if (yy >= 0 && yy < H && xx >= 0 && xx < W) {
                const size_t pix = (size_t)b * HW + (size_t)yy * W + xx;
                #pragma unroll
                for (int k = 0; k < NSIN; ++k) sv += Sin[(size_t)k * sstride + pix];
            }
            rS[i] = 1.f / (sv + EPSV);
        }
        __syncthreads();
    }
    if constexpr (CSTAGE) {
        const unsigned cpk = pack2f16(1.0f / (float)ICg, 1.0f / (float)ICg);
        for (int i = tid; i < NSP; i += 256) {
            const int yy = y0 + i / WSp - 1, xx = x0 + i % WSp - 1;
            const bool ok = (yy >= 0 && yy < H && xx >= 0 && xx < W);
            unsigned* d = (unsigned*)&in_t[0][i * ICP];
            #pragma unroll
            for (int seg = 0; seg < 16; ++seg) d[seg] = ok ? cpk : 0u;
        }
    } else {
        iwrite(0);
    }
    wwrite(0);
    __syncthreads();

    int cur = 0;
    for (int kc = 0; kc < NCH; ++kc) {
        if (kc + 1 < NCH) {
            if constexpr (!CSTAGE) iload(kc + 1);
            wload(kc + 1);
        }
        {
            const _Float16* ib = &in_t[CSTAGE ? 0 : cur][0];
            const _Float16* wb = &w_t[cur][0];
            #pragma unroll
            for (int dy = 0; dy < 3; ++dy) {
                #pragma unroll
                for (int dx = 0; dx < 3; ++dx) {
                    const int tap = dy * 3 + dx;
                    f16x8 bfr[NF];
                    #pragma unroll
                    for (int nf = 0; nf < NF; ++nf) {
                        const int oc = nf * 16 + l15;
                        bfr[nf] = *(const f16x8*)(
                            wb + tap * WOC + oc * 32 + (kq ^ ((oc >> 1) & 3)) * 8);
                    }
                    f16x8 afr[4];
                    #pragma unroll
                    for (int mf = 0; mf < 4; ++mf)
                        afr[mf] = *(const f16x8*)(
                            ib + ((prow + mf + dy) * WSp + l15 + dx) * ICP + kq * 8);
                    #pragma unroll
                    for (int mf = 0; mf < 4; ++mf)
                        #pragma unroll
                        for (int nf = 0; nf < NF; ++nf)
                            acc[mf][nf] = __builtin_amdgcn_mfma_f32_16x16x32_f16(
                                afr[mf], bfr[nf], acc[mf][nf], 0, 0, 0);
                }
            }
        }
        if (kc + 1 < NCH) {
            if constexpr (!CSTAGE) iwrite(cur ^ 1);
            wwrite(cur ^ 1);
            __syncthreads();
            cur ^= 1;
        }
    }

    #pragma unroll
    for (int mf = 0; mf < 4; ++mf) {
        const int gy = y0 + prow + mf;
        const size_t pixbase = (size_t)b * HW + (size_t)gy * W + x0 + kq * 4;
        if constexpr (!UPDATE) {
            #pragma unroll
            for (int nf = 0; nf < NF; ++nf) {
                const int oc = oc0 + nf * 16 + l15;
                if (oc < NW) {
                    #pragma unroll
                    for (int r = 0; r < 4; ++r) {
                        const size_t idx = (pixbase + r) * OST + oc;
                        out[idx] = (_Float16)((float)aux[idx] / (acc[mf][nf][r] + EPSV));
                    }
                }
            }
        } else {
            float s[4] = {0.f, 0.f, 0.f, 0.f};
            #pragma unroll
            for (int nf = 0; nf < NF; ++nf) {
                const int oc = oc0 + nf * 16 + l15;
                #pragma unroll
                for (int r = 0; r < 4; ++r) {
                    const size_t idx = (pixbase + r) * OST + oc;
                    float hv;
                    if constexpr (FIRST) hv = acc[mf][nf][r];
                    else                 hv = (float)out[idx] * acc[mf][nf][r];
                    const _Float16 hq = (_Float16)hv;
                    out[idx] = hq;
                    s[r] += (float)hq;
                }
            }
            #pragma unroll
            for (int mm = 1; mm < 16; mm <<= 1) {
                #pragma unroll
                for (int r = 0; r < 4; ++r) s[r] += __shfl_xor(s[r], mm);
            }
            if (l15 == 0) {
                float* sp_ = Sout + (size_t)split * sstride + pixbase;
                sp_[0] = s[0]; sp_[1] = s[1]; sp_[2] = s[2]; sp_[3] = s[3];
            }
        }
    }
}

// ---------------------------------------------------------------------------
// posty (MFMA 1x1 conv), two-pass; h f16; S = sum of NSIN partials.
// ---------------------------------------------------------------------------
template<int C, int MODE, int NSIN>
__global__ __launch_bounds__(256) void posty_kernel(
    const _Float16* __restrict__ h, const float* __restrict__ S,
    const _Float16* __restrict__ w1h, const float* __restrict__ bias,
    const float* __restrict__ bnst, float* __restrict__ part,
    void* __restrict__ outp, int H, int W, int sst)
{
    constexpr int NF = C / 16, CP = C + 8;
    __shared__ _Float16 a_t[64 * CP];
    __shared__ float rs_t[64];
    __shared__ float sred1[MODE == 0 ? 4 * C : 1];
    __shared__ float sred2[MODE == 0 ? 4 * C : 1];
    __shared__ float pool_t[MODE == 1 ? 16 * (C + 1) : 1];

    const int tid = threadIdx.x;
    const int lane = tid & 63, wave = tid >> 6;
    const int kq = lane >> 4, l15 = lane & 15;
    const int WT = W / 32;
    const int tx = blockIdx.x % WT, ty = blockIdx.x / WT;
    const int b = blockIdx.y;
    const int HW = H * W;

    if (tid < 64) {
        const int gp = (2 * ty + (tid >> 5)) * W + tx * 32 + (tid & 31);
        float sv = 0.f;
        #pragma unroll
        for (int k = 0; k < NSIN; ++k) sv += S[(size_t)k * sst + (size_t)b * HW + gp];
        rs_t[tid] = 1.f / (sv + EPSV);
    }
    __syncthreads();
    for (int i = tid; i < 64 * (C / 8); i += 256) {
        const int sp = i / (C / 8), seg = i % (C / 8);
        const int gp = (2 * ty + (sp >> 5)) * W + tx * 32 + (sp & 31);
        const f16x8 v = *(const f16x8*)(h + ((size_t)b * HW + gp) * C + seg * 8);
        const float f = rs_t[sp];
        unsigned* d = (unsigned*)&a_t[sp * CP + seg * 8];
        d[0] = pack2f16((float)v[0] * f, (float)v[1] * f);
        d[1] = pack2f16((float)v[2] * f, (float)v[3] * f);
        d[2] = pack2f16((float)v[4] * f, (float)v[5] * f);
        d[3] = pack2f16((float)v[6] * f, (float)v[7] * f);
    }
    __syncthreads();

    f32x4 acc[NF];
    #pragma unroll
    for (int nf = 0; nf < NF; ++nf) acc[nf] = (f32x4){0.f, 0.f, 0.f, 0.f};
    #pragma unroll
    for (int kc = 0; kc < C / 32; ++kc) {
        const f16x8 afr = *(const f16x8*)&a_t[(wave * 16 + l15) * CP + kc * 32 + kq * 8];
        #pragma unroll
        for (int nf = 0; nf < NF; ++nf) {
            const f16x8 bfr = *(const f16x8*)(w1h + (size_t)(nf * 16 + l15) * C + kc * 32 + kq * 8);
            acc[nf] = __builtin_amdgcn_mfma_f32_16x16x32_f16(afr, bfr, acc[nf], 0, 0, 0);
        }
    }

    const int pl = wave * 16 + kq * 4;

    if constexpr (MODE == 0) {
        const int wgid = b * gridDim.x + blockIdx.x;
        #pragma unroll
        for (int nf = 0; nf < NF; ++nf) {
            const int oc = nf * 16 + l15;
            const float bv = bias[oc];
            float s1 = 0.f, s2 = 0.f;
            #pragma unroll
            for (int r = 0; r < 4; ++r) {
                const float y = fmaxf(acc[nf][r] + bv, 0.f);
                s1 += y; s2 += y * y;
            }
            s1 += __shfl_xor(s1, 16); s2 += __shfl_xor(s2, 16);
            s1 += __shfl_xor(s1, 32); s2 += __shfl_xor(s2, 32);
            if (kq == 0) {
                sred1[wave * C + oc] = s1;
                sred2[wave * C + oc] = s2;
            }
        }
        __syncthreads();
        for (int oc = tid; oc < C; oc += 256) {
            const float s1 = sred1[oc] + sred1[C + oc] + sred1[2 * C + oc] + sred1[3 * C + oc];
            const float s2 = sred2[oc] + sred2[C + oc] + sred2[2 * C + oc] + sred2[3 * C + oc];
            part[((size_t)wgid * C + oc) * 2 + 0] = s1;
            part[((size_t)wgid * C + oc) * 2 + 1] = s2;
        }
    } else {
        __syncthreads();
        #pragma unroll
        for (int nf = 0; nf < NF; ++nf) {
            const int oc = nf * 16 + l15;
            const float bv = bias[oc];
            #pragma unroll
            for (int r = 0; r < 4; ++r)
                a_t[(pl + r) * CP + oc] = (_Float16)fmaxf(acc[nf][r] + bv, 0.f);
        }
        __syncthreads();
        const int Wo = W >> 1;
        if constexpr (MODE == 2) {
            for (int i = tid; i < 16 * C; i += 256) {
                const int ox = i % 16, c = i / 16;
                const float y00 = (float)a_t[(2 * ox) * CP + c];
                const float y01 = (float)a_t[(2 * ox + 1) * CP + c];
                const float y10 = (float)a_t[(32 + 2 * ox) * CP + c];
                const float y11 = (float)a_t[(32 + 2 * ox + 1) * CP + c];
                const float v = (y00 + y01 + y10 + y11) * 0.25f * bnst[c] + bnst[C + c];
                ((float*)outp)[(((size_t)b * C + c) * (size_t)(H >> 1) + ty) * Wo + tx * 16 + ox] = v;
            }
        } else {
            for (int i = tid; i < 16 * C; i += 256) {
                const int ox = i / C, c = i % C;
                const float y00 = (float)a_t[(2 * ox) * CP + c];
                const float y01 = (float)a_t[(2 * ox + 1) * CP + c];
                const float y10 = (float)a_t[(32 + 2 * ox) * CP + c];
                const float y11 = (float)a_t[(32 + 2 * ox + 1) * CP + c];
                pool_t[ox * (C + 1) + c] =
                    fmaxf((y00 + y01 + y10 + y11) * 0.25f * bnst[c] + bnst[C + c], 0.f);
            }
            __syncthreads();
            const int px = tid >> 4, prt = tid & 15;
            float ps = 0.f;
            for (int c = prt; c < C; c += 16) ps += pool_t[px * (C + 1) + c];
            ps += __shfl_xor(ps, 1); ps += __shfl_xor(ps, 2);
            ps += __shfl_xor(ps, 4); ps += __shfl_xor(ps, 8);
            const float rs = 1.f / (ps + EPSV);
            _Float16* xo = (_Float16*)outp;
            const size_t obase = ((size_t)b * (HW >> 2) + (size_t)ty * Wo + tx * 16 + px) * C;
            for (int c = prt; c < C; c += 16)
                xo[obase + c] = (_Float16)(pool_t[px * (C + 1) + c] * rs);
        }
    }
}

template<int C>
__global__ __launch_bounds__(256) void stats_kernel(const float* __restrict__ part, int nwg, float invM,
                                                    const float* __restrict__ gamma,
                                                    const float* __restrict__ beta,
                                                    float* __restrict__ stats)
{
    const int oc = blockIdx.x;
    const int tid = threadIdx.x;
    float s1 = 0.f, s2 = 0.f;
    for (int w = tid; w < nwg; w += 256) {
        s1 += part[((size_t)w * C + oc) * 2 + 0];
        s2 += part[((size_t)w * C + oc) * 2 + 1];
    }
    __shared__ float r1[4], r2[4];
    #pragma unroll
    for (int m = 32; m; m >>= 1) { s1 += __shfl_xor(s1, m, 64); s2 += __shfl_xor(s2, m, 64); }
    if ((tid & 63) == 0) { r1[tid >> 6] = s1; r2[tid >> 6] = s2; }
    __syncthreads();
    if (tid == 0) {
        s1 = r1[0] + r1[1] + r1[2] + r1[3];
        s2 = r2[0] + r2[1] + r2[2] + r2[3];
        const float mean = s1 * invM;
        const float var  = s2 * invM - mean * mean;
        const float rstd = rsqrtf(var + BNEPS);
        const float scale = gamma[oc] * rstd;
        stats[oc]     = scale;
        stats[C + oc] = beta[oc] - mean * scale;
    }
}

// ---------------------------------------------------------------------------
extern "C" void kernel_launch(void* const* d_in, const int* in_sizes, int n_in,
                              void* d_out, int out_size, void* d_ws, size_t ws_size,
                              hipStream_t stream)
{
    const float* x = (const float*)d_in[0];
    float* ws      = (float*)d_ws;
    float* S       = ws;                    //    262,144 f32
    float* part    = S + 262144;            //  1,048,576 f32
    float* bnstats = part + 1048576;        //        512 f32
    _Float16* h      = (_Float16*)(bnstats + 512); // 16,777,216 f16
    _Float16* xnh    = h + 16777216;               //  4,194,304 f16
    _Float16* ratioh = xnh + 4194304;              //  4,194,304 f16 (block2)
    _Float16* wA1h   = ratioh + 4194304;           //     73,728 f16
    _Float16* wB1h   = wA1h + 73728;               //     73,728 f16
    _Float16* wA2h   = wB1h + 73728;               //    294,912 f16
    _Float16* wB2h   = wA2h + 294912;              //    294,912 f16
    _Float16* w1h0   = wB2h + 294912;              //      4,096 f16
    _Float16* w1h1   = w1h0 + 4096;                //     16,384 f16
    _Float16* w1h2   = w1h1 + 16384;               //     65,536 f16
    _Float16* wA0h   = w1h2 + 65536;               //      9,216 f16
    _Float16* wB0h   = wA0h + 9216;                //     18,432 f16

    const int B = 16;

    prep_all_kernel<<<784, 256, 0, stream>>>(
        (const float*)d_in[1], (const float*)d_in[2],
        (const float*)d_in[6], (const float*)d_in[7],
        (const float*)d_in[11], (const float*)d_in[12],
        wA0h, wB0h, wA1h, wB1h, wA2h, wB2h, w1h0, w1h1, w1h2);

    // ---------------- Block 0: Cin=3, Cout=64, 128x128 ----------------
    {
        const int H = 128, W = 128, HW = H * W, npx = B * HW;
        xn0_kernel<<<npx / 256, 256, 0, stream>>>(x, xnh, npx, HW);
        mffuse_kernel<64, 32, 1, 1, 4, 4, true>
            <<<dim3(8, 8, B), 256, 0, stream>>>(h, wA0h, wB0h, xnh, S, H, W);
        for (int it = 1; it < 5; ++it)
            mffuse_kernel<64, 32, 1, 1, 4, 4, false>
                <<<dim3(8, 8, B), 256, 0, stream>>>(h, wA0h, wB0h, xnh, S, H, W);
        dim3 pg((W / 32) * (H / 2), B);
        posty_kernel<64, 0, 1><<<pg, 256, 0, stream>>>(h, S, w1h0, (const float*)d_in[3],
                                                       nullptr, part, nullptr, H, W, npx);
        stats_kernel<64><<<64, 256, 0, stream>>>(part, pg.x * pg.y, 1.0f / (float)npx,
                                                 (const float*)d_in[4], (const float*)d_in[5], bnstats);
        posty_kernel<64, 1, 1><<<pg, 256, 0, stream>>>(h, S, w1h0, (const float*)d_in[3],
                                                       bnstats, nullptr, xnh, H, W, npx);
    }

    // ---------------- Block 1: Cin=64, Cout=128, 64x64 ----------------
    {
        const int H = 64, W = 64, HW = H * W, npx = B * HW;
        mffuse_kernel<128, 64, 4, 2, 64, 64, true>
            <<<dim3(4, 4, B), 256, 0, stream>>>(h, wA1h, wB1h, xnh, S, H, W);
        for (int it = 1; it < 5; ++it)
            mffuse_kernel<128, 64, 4, 2, 64, 64, false>
                <<<dim3(4, 4, B), 256, 0, stream>>>(h, wA1h, wB1h, xnh, S, H, W);
        dim3 pg((W / 32) * (H / 2), B);
        posty_kernel<128, 0, 1><<<pg, 256, 0, stream>>>(h, S, w1h1, (const float*)d_in[8],
                                                        nullptr, part, nullptr, H, W, npx);
        stats_kernel<128><<<128, 256, 0, stream>>>(part, pg.x * pg.y, 1.0f / (float)npx,
                                                   (const float*)d_in[9], (const float*)d_in[10], bnstats);
        posty_kernel<128, 1, 1><<<pg, 256, 0, stream>>>(h, S, w1h1, (const float*)d_in[8],
                                                        bnstats, nullptr, xnh, H, W, npx);
    }

    // ---------------- Block 2: Cin=128, Cout=256, 32x32 (mfconv5 path) ------
    {
        const int H = 32, W = 32, HW = H * W, npx = B * HW;
        mfconv5<256, 128, 2, 128, 128, 1, true, false, true>
            <<<dim3(4, 2, B), 256, 0, stream>>>(h, wA2h, xnh, ratioh, S, nullptr, H, W, npx);
        mfconv5<128, 256, 4, 256, 256, 1, false, true, true>
            <<<dim3(8, 2, B), 256, 0, stream>>>(ratioh, wB2h, nullptr, h, nullptr, S, H, W, npx);
        for (int it = 1; it < 5; ++it) {
            mfconv5<256, 128, 2, 128, 128, 4, true, false, false>
                <<<dim3(4, 2, B), 256, 0, stream>>>(h, wA2h, xnh, ratioh, S, nullptr, H, W, npx);
            mfconv5<128, 256, 4, 256, 256, 1, false, true, false>
                <<<dim3(8, 2, B), 256, 0, stream>>>(ratioh, wB2h, nullptr, h, nullptr, S, H, W, npx);
        }
        dim3 pg((W / 32) * (H / 2), B);
        posty_kernel<256, 0, 4><<<pg, 256, 0, stream>>>(h, S, w1h2, (const float*)d_in[13],
                                                        nullptr, part, nullptr, H, W, npx);
        stats_kernel<256><<<256, 256, 0, stream>>>(part, pg.x * pg.y, 1.0f / (float)npx,
                                                   (const float*)d_in[14], (const float*)d_in[15], bnstats);
        posty_kernel<256, 2, 4><<<pg, 256, 0, stream>>>(h, S, w1h2, (const float*)d_in[13],
                                                        bnstats, nullptr, d_out, H, W, npx);
    }
}

// Round 13
// 807.860 us; speedup vs baseline: 1.2319x; 1.2319x over previous
//
#include <hip/hip_runtime.h>

#define EPSV  1e-20f
#define BNEPS 1e-5f

typedef _Float16 f16x8 __attribute__((ext_vector_type(8)));
typedef _Float16 f16x4 __attribute__((ext_vector_type(4)));
typedef float    f32x4 __attribute__((ext_vector_type(4)));

__device__ inline unsigned pack2f16(float a, float b) {
    unsigned short ua = __builtin_bit_cast(unsigned short, (_Float16)a);
    unsigned short ub = __builtin_bit_cast(unsigned short, (_Float16)b);
    return ((unsigned)ub << 16) | ua;
}

// ---------------------------------------------------------------------------
// prep_generic: wn = |w|/(sum+eps), chunked GEMM layouts (blocks 1/2):
//   wBh[kc(ci/32)][tap ][co(COUT)][ci%32]
//   wAh[kc(co/32)][tapf][ci(CIN) ][co%32]
// ---------------------------------------------------------------------------
__device__ __forceinline__ void prep_generic(const float* __restrict__ w, int CIN, int COUT,
                                             _Float16* __restrict__ wAh, _Float16* __restrict__ wBh,
                                             int co, int tid, float* red)
{
    const int N = CIN * 9;
    const float* wrow = w + (size_t)co * N;
    float s = 0.f;
    for (int i = tid; i < N; i += 256) s += fabsf(wrow[i]);
    #pragma unroll
    for (int m = 32; m; m >>= 1) s += __shfl_xor(s, m, 64);
    if ((tid & 63) == 0) red[tid >> 6] = s;
    __syncthreads();
    s = red[0] + red[1] + red[2] + red[3];
    const float rn = 1.f / (s + EPSV);
    for (int i = tid; i < N; i += 256) {
        const int ci = i / 9, tap = i % 9;
        const int ky = tap / 3, kx = tap % 3;
        const float v = fabsf(wrow[i]) * rn;
        const int tf = (2 - ky) * 3 + (2 - kx);
        wBh[(((size_t)(ci >> 5) * 9 + tap) * COUT + co) * 32 + (ci & 31)] = (_Float16)v;
        wAh[(((size_t)(co >> 5) * 9 + tf) * CIN + ci) * 32 + (co & 31)] = (_Float16)v;
    }
}

// All weight prep in one launch. Sections by blockIdx.x:
//  [0,64): block0 (CIN=3): wA0h[kc][tf][16ci][32co] (mfconv5 ratio layout),
//          wB0h[co][64k] (mf0u im2col layout, k = tap*4+ci, zero-padded)
//  [64,192): block1; [192,448): block2
//  [448,464): w1h0; [464,528): w1h1; [528,784): w1h2
__global__ __launch_bounds__(256) void prep_all_kernel(
    const float* __restrict__ w0,  const float* __restrict__ w1_0,
    const float* __restrict__ wb1, const float* __restrict__ w1_1,
    const float* __restrict__ wb2, const float* __restrict__ w1_2,
    _Float16* __restrict__ wA0h, _Float16* __restrict__ wB0h,
    _Float16* __restrict__ wA1h, _Float16* __restrict__ wB1h,
    _Float16* __restrict__ wA2h, _Float16* __restrict__ wB2h,
    _Float16* __restrict__ w1h0, _Float16* __restrict__ w1h1, _Float16* __restrict__ w1h2)
{
    __shared__ float red[4];
    const int bid = blockIdx.x, tid = threadIdx.x;
    if (bid < 64) {
        const int co = bid;
        float s = (tid < 27) ? fabsf(w0[co * 27 + tid]) : 0.f;
        #pragma unroll
        for (int m = 32; m; m >>= 1) s += __shfl_xor(s, m, 64);
        if ((tid & 63) == 0) red[tid >> 6] = s;
        __syncthreads();
        s = red[0] + red[1] + red[2] + red[3];
        const float rn = 1.f / (s + EPSV);
        // wB0h: [co][64], k = tap*4+ci (36 used, rest zero)
        if (tid < 64) {
            const int tap = tid >> 2, ci = tid & 3;
            const float v = (tap < 9 && ci < 3) ? fabsf(w0[co * 27 + ci * 9 + tap]) * rn : 0.f;
            wB0h[co * 64 + tid] = (_Float16)v;
        }
        // wA0h: [kc(co/32)][tf][ci(16)][co%32], ci>=3 zero
        for (int i = tid; i < 9 * 16; i += 256) {
            const int tf = i / 16, ci = i % 16;
            float v = 0.f;
            if (ci < 3) {
                const int tap = (2 - tf / 3) * 3 + (2 - tf % 3);
                v = fabsf(w0[co * 27 + ci * 9 + tap]) * rn;
            }
            wA0h[((((size_t)(co >> 5) * 9 + tf) * 16 + ci) * 32) + (co & 31)] = (_Float16)v;
        }
    } else if (bid < 192) {
        prep_generic(wb1, 64, 128, wA1h, wB1h, bid - 64, tid, red);
    } else if (bid < 448) {
        prep_generic(wb2, 128, 256, wA2h, wB2h, bid - 192, tid, red);
    } else if (bid < 464) {
        const int i = (bid - 448) * 256 + tid; w1h0[i] = (_Float16)w1_0[i];
    } else if (bid < 528) {
        const int i = (bid - 464) * 256 + tid; w1h1[i] = (_Float16)w1_1[i];
    } else {
        const int i = (bid - 528) * 256 + tid; w1h2[i] = (_Float16)w1_2[i];
    }
}

// ---------------------------------------------------------------------------
// xn prep (block0): x NCHW fp32 -> xn [pix][4] f16 (ch3=0).
// ---------------------------------------------------------------------------
__global__ __launch_bounds__(256) void xn0_kernel(const float* __restrict__ x,
                                                  _Float16* __restrict__ xn4,
                                                  int npx, int HW)
{
    const int p = blockIdx.x * 256 + threadIdx.x;
    if (p >= npx) return;
    const int b = p / HW, r = p % HW;
    const float* ip = x + (size_t)b * 3 * HW + r;
    const float v0 = fmaxf(ip[0], 0.f), v1 = fmaxf(ip[HW], 0.f), v2 = fmaxf(ip[2 * HW], 0.f);
    const float rs = 1.f / (v0 + v1 + v2 + EPSV);
    unsigned* d = (unsigned*)(xn4 + (size_t)p * 4);
    d[0] = pack2f16(v0 * rs, v1 * rs);
    d[1] = pack2f16(v2 * rs, 0.f);
}

// ---------------------------------------------------------------------------
// mfconv5: NHWC f16 MFMA implicit-GEMM 3x3 conv, high-reuse register tiling.
//   Tile = 16x16 px, 4 waves; wave owns 4 M-frags (64 px) x NF oc-frags.
//   Per-32k chunks, input+weights double-buffered in LDS (one barrier/chunk).
//   NORM_IN: input scaled by 1/(Sum_k Sin_k + eps) while staging (ratio conv).
//   FIRST && NORM_IN: stage CONSTANT 1/ICg (h==1, S==C) -- no input/S reads.
//   !UPDATE: out = aux/(acc+eps) f16, stride OST, only oc<NW written.
//   UPDATE : FIRST ? h = acc : h *= acc (f16 RMW); S partials at split*sstride.
// Weights global: [kc][tap][n(OCg)][32]; LDS [tap][oc][32] XOR-swizzled.
// ---------------------------------------------------------------------------
template<int ICg, int OCg, int NSPLIT, int OST, int NW, int NSIN,
         bool NORM_IN, bool UPDATE, bool FIRST>
__global__ __launch_bounds__(256, 1) void mfconv5(
    const _Float16* __restrict__ in, const _Float16* __restrict__ wgt,
    const _Float16* __restrict__ aux, _Float16* __restrict__ out,
    const float* __restrict__ Sin, float* __restrict__ Sout,
    int H, int W, int sstride)
{
    constexpr bool CSTAGE = FIRST && NORM_IN;
    constexpr int OCWG = OCg / NSPLIT;
    constexpr int NF = OCWG / 16;
    constexpr int HS = 18, WSp = 18, NSP = HS * WSp;
    constexpr int ICP = 40;
    constexpr int NCH = ICg / 32;
    constexpr int LS = (NSPLIT == 4) ? 2 : (NSPLIT == 2) ? 1 : 0;
    constexpr int NLD = NSP * 4;
    constexpr int IREG = (NLD + 255) / 256;
    constexpr int WOC = OCWG * 32;
    constexpr int NWLD = 9 * OCWG * 4;
    constexpr int WREG = (NWLD + 255) / 256;
    static_assert(OCWG % 16 == 0 && ICg % 32 == 0, "cfg");

    __shared__ _Float16 in_t[CSTAGE ? 1 : 2][NSP * ICP];
    __shared__ _Float16 w_t[2][9 * WOC];
    __shared__ float rS[(NORM_IN && !FIRST) ? NSP : 1];

    const int tid = threadIdx.x;
    const int lane = tid & 63, wave = tid >> 6;
    const int kq = lane >> 4, l15 = lane & 15;
    const int split = blockIdx.x & (NSPLIT - 1);
    const int tx = blockIdx.x >> LS;
    const int x0 = tx * 16, y0 = blockIdx.y * 16, b = blockIdx.z;
    const int HW = H * W;
    const int oc0 = split * OCWG;

    f16x8 ild[CSTAGE ? 1 : IREG];
    f16x8 wld[WREG];

    auto iload = [&](int kc) {
        #pragma unroll
        for (int r = 0; r < IREG; ++r) {
            const int i = tid + r * 256;
            f16x8 v = {0, 0, 0, 0, 0, 0, 0, 0};
            if (i < NLD) {
                const int sp = i >> 2, seg = i & 3;
                const int yy = y0 + sp / WSp - 1, xx = x0 + sp % WSp - 1;
                if (yy >= 0 && yy < H && xx >= 0 && xx < W)
                    v = __builtin_nontemporal_load((const f16x8*)(in +
                        ((size_t)b * HW + (size_t)yy * W + xx) * ICg + kc * 32 + seg * 8));
            }
            ild[r] = v;
        }
    };
    auto wload = [&](int kc) {
        #pragma unroll
        for (int r = 0; r < WREG; ++r) {
            const int j = tid + r * 256;
            if (j < NWLD) {
                const int tap = j / (OCWG * 4), rem = j % (OCWG * 4);
                const int oc = rem >> 2, e = rem & 3;
                wld[r] = *(const f16x8*)(wgt +
                    (((size_t)kc * 9 + tap) * OCg + oc0 + oc) * 32 + e * 8);
            }
        }
    };
    auto iwrite = [&](int buf) {
        #pragma unroll
        for (int r = 0; r < IREG; ++r) {
            const int i = tid + r * 256;
            if (i < NLD) {
                const int sp = i >> 2, seg = i & 3;
                if constexpr (NORM_IN && !FIRST) {
                    const float f = rS[sp];
                    unsigned* d = (unsigned*)&in_t[buf][sp * ICP + seg * 8];
                    d[0] = pack2f16((float)ild[r][0] * f, (float)ild[r][1] * f);
                    d[1] = pack2f16((float)ild[r][2] * f, (float)ild[r][3] * f);
                    d[2] = pack2f16((float)ild[r][4] * f, (float)ild[r][5] * f);
                    d[3] = pack2f16((float)ild[r][6] * f, (float)ild[r][7] * f);
                } else {
                    *(f16x8*)&in_t[buf][sp * ICP + seg * 8] = ild[r];
                }
            }
        }
    };
    auto wwrite = [&](int buf) {
        #pragma unroll
        for (int r = 0; r < WREG; ++r) {
            const int j = tid + r * 256;
            if (j < NWLD) {
                const int tap = j / (OCWG * 4), rem = j % (OCWG * 4);
                const int oc = rem >> 2, e = rem & 3;
                const int slot = e ^ ((oc >> 1) & 3);
                *(f16x8*)&w_t[buf][tap * WOC + oc * 32 + slot * 8] = wld[r];
            }
        }
    };

    const int prow = wave * 4;

    f32x4 acc[4][NF];
    #pragma unroll
    for (int mf = 0; mf < 4; ++mf)
        #pragma unroll
        for (int nf = 0; nf < NF; ++nf) acc[mf][nf] = (f32x4){0.f, 0.f, 0.f, 0.f};

    if constexpr (!CSTAGE) iload(0);
    wload(0);
    if constexpr (NORM_IN && !FIRST) {
        for (int i = tid; i < NSP; i += 256) {
            const int yy = y0 + i / WSp - 1, xx = x0 + i % WSp - 1;
            float sv = 0.f;
            if (yy >= 0 && yy < H && xx >= 0 && xx < W) {
                const size_t pix = (size_t)b * HW + (size_t)yy * W + xx;
                #pragma unroll
                for (int k = 0; k < NSIN; ++k) sv += Sin[(size_t)k * sstride + pix];
            }
            rS[i] = 1.f / (sv + EPSV);
        }
        __syncthreads();
    }
    if constexpr (CSTAGE) {
        const unsigned cpk = pack2f16(1.0f / (float)ICg, 1.0f / (float)ICg);
        for (int i = tid; i < NSP; i += 256) {
            const int yy = y0 + i / WSp - 1, xx = x0 + i % WSp - 1;
            const bool ok = (yy >= 0 && yy < H && xx >= 0 && xx < W);
            unsigned* d = (unsigned*)&in_t[0][i * ICP];
            #pragma unroll
            for (int seg = 0; seg < 16; ++seg) d[seg] = ok ? cpk : 0u;
        }
    } else {
        iwrite(0);
    }
    wwrite(0);
    __syncthreads();

    int cur = 0;
    for (int kc = 0; kc < NCH; ++kc) {
        if (kc + 1 < NCH) {
            if constexpr (!CSTAGE) iload(kc + 1);
            wload(kc + 1);
        }
        {
            const _Float16* ib = &in_t[CSTAGE ? 0 : cur][0];
            const _Float16* wb = &w_t[cur][0];
            #pragma unroll
            for (int dy = 0; dy < 3; ++dy) {
                #pragma unroll
                for (int dx = 0; dx < 3; ++dx) {
                    const int tap = dy * 3 + dx;
                    f16x8 bfr[NF];
                    #pragma unroll
                    for (int nf = 0; nf < NF; ++nf) {
                        const int oc = nf * 16 + l15;
                        bfr[nf] = *(const f16x8*)(
                            wb + tap * WOC + oc * 32 + (kq ^ ((oc >> 1) & 3)) * 8);
                    }
                    f16x8 afr[4];
                    #pragma unroll
                    for (int mf = 0; mf < 4; ++mf)
                        afr[mf] = *(const f16x8*)(
                            ib + ((prow + mf + dy) * WSp + l15 + dx) * ICP + kq * 8);
                    #pragma unroll
                    for (int mf = 0; mf < 4; ++mf)
                        #pragma unroll
                        for (int nf = 0; nf < NF; ++nf)
                            acc[mf][nf] = __builtin_amdgcn_mfma_f32_16x16x32_f16(
                                afr[mf], bfr[nf], acc[mf][nf], 0, 0, 0);
                }
            }
        }
        if (kc + 1 < NCH) {
            if constexpr (!CSTAGE) iwrite(cur ^ 1);
            wwrite(cur ^ 1);
            __syncthreads();
            cur ^= 1;
        }
    }

    #pragma unroll
    for (int mf = 0; mf < 4; ++mf) {
        const int gy = y0 + prow + mf;
        const size_t pixbase = (size_t)b * HW + (size_t)gy * W + x0 + kq * 4;
        if constexpr (!UPDATE) {
            #pragma unroll
            for (int nf = 0; nf < NF; ++nf) {
                const int oc = oc0 + nf * 16 + l15;
                if (oc < NW) {
                    #pragma unroll
                    for (int r = 0; r < 4; ++r) {
                        const size_t idx = (pixbase + r) * OST + oc;
                        out[idx] = (_Float16)((float)aux[idx] / (acc[mf][nf][r] + EPSV));
                    }
                }
            }
        } else {
            float s[4] = {0.f, 0.f, 0.f, 0.f};
            #pragma unroll
            for (int nf = 0; nf < NF; ++nf) {
                const int oc = oc0 + nf * 16 + l15;
                #pragma unroll
                for (int r = 0; r < 4; ++r) {
                    const size_t idx = (pixbase + r) * OST + oc;
                    float hv;
                    if constexpr (FIRST) hv = acc[mf][nf][r];
                    else                 hv = (float)out[idx] * acc[mf][nf][r];
                    const _Float16 hq = (_Float16)hv;
                    out[idx] = hq;
                    s[r] += (float)hq;
                }
            }
            #pragma unroll
            for (int mm = 1; mm < 16; mm <<= 1) {
                #pragma unroll
                for (int r = 0; r < 4; ++r) s[r] += __shfl_xor(s[r], mm);
            }
            if (l15 == 0) {
                float* sp_ = Sout + (size_t)split * sstride + pixbase;
                sp_[0] = s[0]; sp_[1] = s[1]; sp_[2] = s[2]; sp_[3] = s[3];
            }
        }
    }
}

// ---------------------------------------------------------------------------
// Block0 update conv (3 -> 64) via im2col MFMA, h f16 (FIRST: write, else RMW).
// ---------------------------------------------------------------------------
template<bool FIRST>
__global__ __launch_bounds__(256) void mf0u_kernel(
    const _Float16* __restrict__ ratio4, const _Float16* __restrict__ wB0h,
    _Float16* __restrict__ h, float* __restrict__ Sout, int H, int W)
{
    constexpr int TW = 16;
    __shared__ _Float16 a_t[64 * 72];

    const int tid = threadIdx.x;
    const int lane = tid & 63, wave = tid >> 6;
    const int kq = lane >> 4, l15 = lane & 15;
    const int x0 = blockIdx.x * TW, y0 = blockIdx.y * 4, b = blockIdx.z;
    const int HW = H * W;

    for (int i = tid; i < 64 * 72 / 2; i += 256) ((unsigned*)a_t)[i] = 0;
    __syncthreads();
    for (int i = tid; i < 576; i += 256) {
        const int px = i / 9, tap = i % 9;
        const int py = px / TW, pxx = px % TW;
        const int yy = y0 + py + tap / 3 - 1, xx = x0 + pxx + tap % 3 - 1;
        if (yy >= 0 && yy < H && xx >= 0 && xx < W)
            *(f16x4*)&a_t[px * 72 + tap * 4] =
                *(const f16x4*)(ratio4 + ((size_t)b * HW + (size_t)yy * W + xx) * 4);
    }
    __syncthreads();

    f32x4 acc[4];
    #pragma unroll
    for (int nf = 0; nf < 4; ++nf) acc[nf] = (f32x4){0.f, 0.f, 0.f, 0.f};
    #pragma unroll
    for (int kc = 0; kc < 2; ++kc) {
        const f16x8 afr = *(const f16x8*)&a_t[(wave * 16 + l15) * 72 + kc * 32 + kq * 8];
        #pragma unroll
        for (int nf = 0; nf < 4; ++nf) {
            const f16x8 bfr = *(const f16x8*)(wB0h + (size_t)(nf * 16 + l15) * 64 + kc * 32 + kq * 8);
            acc[nf] = __builtin_amdgcn_mfma_f32_16x16x32_f16(afr, bfr, acc[nf], 0, 0, 0);
        }
    }

    const int pl = wave * 16 + kq * 4;
    const size_t pixbase = (size_t)b * HW + (size_t)(y0 + pl / TW) * W + x0 + pl % TW;
    float s[4] = {0.f, 0.f, 0.f, 0.f};
    #pragma unroll
    for (int nf = 0; nf < 4; ++nf) {
        const int oc = nf * 16 + l15;
        #pragma unroll
        for (int r = 0; r < 4; ++r) {
            const size_t idx = (pixbase + r) * 64 + oc;
            float hv;
            if constexpr (FIRST) hv = acc[nf][r];
            else                 hv = (float)h[idx] * acc[nf][r];
            const _Float16 hq = (_Float16)hv;
            h[idx] = hq;
            s[r] += (float)hq;
        }
    }
    #pragma unroll
    for (int mm = 1; mm < 16; mm <<= 1) {
        #pragma unroll
        for (int r = 0; r < 4; ++r) s[r] += __shfl_xor(s[r], mm);
    }
    if (l15 == 0) {
        float* sp_ = Sout + pixbase;
        sp_[0] = s[0]; sp_[1] = s[1]; sp_[2] = s[2]; sp_[3] = s[3];
    }
}

// ---------------------------------------------------------------------------
// posty (MFMA 1x1 conv), two-pass; h f16; S = sum of NSIN partials.
//   MODE 0: stats partials.
//   MODE 1: pool+BN -> relu+L1-normalize -> xn f16 NHWC (next block input).
//   MODE 2: pool+BN -> fp32 NCHW (d_out).
// ---------------------------------------------------------------------------
template<int C, int MODE, int NSIN>
__global__ __launch_bounds__(256) void posty_kernel(
    const _Float16* __restrict__ h, const float* __restrict__ S,
    const _Float16* __restrict__ w1h, const float* __restrict__ bias,
    const float* __restrict__ bnst, float* __restrict__ part,
    void* __restrict__ outp, int H, int W, int sst)
{
    constexpr int NF = C / 16, CP = C + 8;
    __shared__ _Float16 a_t[64 * CP];
    __shared__ float rs_t[64];
    __shared__ float sred1[MODE == 0 ? 4 * C : 1];
    __shared__ float sred2[MODE == 0 ? 4 * C : 1];
    __shared__ float pool_t[MODE == 1 ? 16 * (C + 1) : 1];

    const int tid = threadIdx.x;
    const int lane = tid & 63, wave = tid >> 6;
    const int kq = lane >> 4, l15 = lane & 15;
    const int WT = W / 32;
    const int tx = blockIdx.x % WT, ty = blockIdx.x / WT;
    const int b = blockIdx.y;
    const int HW = H * W;

    if (tid < 64) {
        const int gp = (2 * ty + (tid >> 5)) * W + tx * 32 + (tid & 31);
        float sv = 0.f;
        #pragma unroll
        for (int k = 0; k < NSIN; ++k) sv += S[(size_t)k * sst + (size_t)b * HW + gp];
        rs_t[tid] = 1.f / (sv + EPSV);
    }
    __syncthreads();
    for (int i = tid; i < 64 * (C / 8); i += 256) {
        const int sp = i / (C / 8), seg = i % (C / 8);
        const int gp = (2 * ty + (sp >> 5)) * W + tx * 32 + (sp & 31);
        const f16x8 v = *(const f16x8*)(h + ((size_t)b * HW + gp) * C + seg * 8);
        const float f = rs_t[sp];
        unsigned* d = (unsigned*)&a_t[sp * CP + seg * 8];
        d[0] = pack2f16((float)v[0] * f, (float)v[1] * f);
        d[1] = pack2f16((float)v[2] * f, (float)v[3] * f);
        d[2] = pack2f16((float)v[4] * f, (float)v[5] * f);
        d[3] = pack2f16((float)v[6] * f, (float)v[7] * f);
    }
    __syncthreads();

    f32x4 acc[NF];
    #pragma unroll
    for (int nf = 0; nf < NF; ++nf) acc[nf] = (f32x4){0.f, 0.f, 0.f, 0.f};
    #pragma unroll
    for (int kc = 0; kc < C / 32; ++kc) {
        const f16x8 afr = *(const f16x8*)&a_t[(wave * 16 + l15) * CP + kc * 32 + kq * 8];
        #pragma unroll
        for (int nf = 0; nf < NF; ++nf) {
            const f16x8 bfr = *(const f16x8*)(w1h + (size_t)(nf * 16 + l15) * C + kc * 32 + kq * 8);
            acc[nf] = __builtin_amdgcn_mfma_f32_16x16x32_f16(afr, bfr, acc[nf], 0, 0, 0);
        }
    }

    const int pl = wave * 16 + kq * 4;

    if constexpr (MODE == 0) {
        const int wgid = b * gridDim.x + blockIdx.x;
        #pragma unroll
        for (int nf = 0; nf < NF; ++nf) {
            const int oc = nf * 16 + l15;
            const float bv = bias[oc];
            float s1 = 0.f, s2 = 0.f;
            #pragma unroll
            for (int r = 0; r < 4; ++r) {
                const float y = fmaxf(acc[nf][r] + bv, 0.f);
                s1 += y; s2 += y * y;
            }
            s1 += __shfl_xor(s1, 16); s2 += __shfl_xor(s2, 16);
            s1 += __shfl_xor(s1, 32); s2 += __shfl_xor(s2, 32);
            if (kq == 0) {
                sred1[wave * C + oc] = s1;
                sred2[wave * C + oc] = s2;
            }
        }
        __syncthreads();
        for (int oc = tid; oc < C; oc += 256) {
            const float s1 = sred1[oc] + sred1[C + oc] + sred1[2 * C + oc] + sred1[3 * C + oc];
            const float s2 = sred2[oc] + sred2[C + oc] + sred2[2 * C + oc] + sred2[3 * C + oc];
            part[((size_t)wgid * C + oc) * 2 + 0] = s1;
            part[((size_t)wgid * C + oc) * 2 + 1] = s2;
        }
    } else {
        __syncthreads();
        #pragma unroll
        for (int nf = 0; nf < NF; ++nf) {
            const int oc = nf * 16 + l15;
            const float bv = bias[oc];
            #pragma unroll
            for (int r = 0; r < 4; ++r)
                a_t[(pl + r) * CP + oc] = (_Float16)fmaxf(acc[nf][r] + bv, 0.f);
        }
        __syncthreads();
        const int Wo = W >> 1;
        if constexpr (MODE == 2) {
            for (int i = tid; i < 16 * C; i += 256) {
                const int ox = i % 16, c = i / 16;
                const float y00 = (float)a_t[(2 * ox) * CP + c];
                const float y01 = (float)a_t[(2 * ox + 1) * CP + c];
                const float y10 = (float)a_t[(32 + 2 * ox) * CP + c];
                const float y11 = (float)a_t[(32 + 2 * ox + 1) * CP + c];
                const float v = (y00 + y01 + y10 + y11) * 0.25f * bnst[c] + bnst[C + c];
                ((float*)outp)[(((size_t)b * C + c) * (size_t)(H >> 1) + ty) * Wo + tx * 16 + ox] = v;
            }
        } else {
            for (int i = tid; i < 16 * C; i += 256) {
                const int ox = i / C, c = i % C;
                const float y00 = (float)a_t[(2 * ox) * CP + c];
                const float y01 = (float)a_t[(2 * ox + 1) * CP + c];
                const float y10 = (float)a_t[(32 + 2 * ox) * CP + c];
                const float y11 = (float)a_t[(32 + 2 * ox + 1) * CP + c];
                pool_t[ox * (C + 1) + c] =
                    fmaxf((y00 + y01 + y10 + y11) * 0.25f * bnst[c] + bnst[C + c], 0.f);
            }
            __syncthreads();
            const int px = tid >> 4, prt = tid & 15;
            float ps = 0.f;
            for (int c = prt; c < C; c += 16) ps += pool_t[px * (C + 1) + c];
            ps += __shfl_xor(ps, 1); ps += __shfl_xor(ps, 2);
            ps += __shfl_xor(ps, 4); ps += __shfl_xor(ps, 8);
            const float rs = 1.f / (ps + EPSV);
            _Float16* xo = (_Float16*)outp;
            const size_t obase = ((size_t)b * (HW >> 2) + (size_t)ty * Wo + tx * 16 + px) * C;
            for (int c = prt; c < C; c += 16)
                xo[obase + c] = (_Float16)(pool_t[px * (C + 1) + c] * rs);
        }
    }
}

template<int C>
__global__ __launch_bounds__(256) void stats_kernel(const float* __restrict__ part, int nwg, float invM,
                                                    const float* __restrict__ gamma,
                                                    const float* __restrict__ beta,
                                                    float* __restrict__ stats)
{
    const int oc = blockIdx.x;
    const int tid = threadIdx.x;
    float s1 = 0.f, s2 = 0.f;
    for (int w = tid; w < nwg; w += 256) {
        s1 += part[((size_t)w * C + oc) * 2 + 0];
        s2 += part[((size_t)w * C + oc) * 2 + 1];
    }
    __shared__ float r1[4], r2[4];
    #pragma unroll
    for (int m = 32; m; m >>= 1) { s1 += __shfl_xor(s1, m, 64); s2 += __shfl_xor(s2, m, 64); }
    if ((tid & 63) == 0) { r1[tid >> 6] = s1; r2[tid >> 6] = s2; }
    __syncthreads();
    if (tid == 0) {
        s1 = r1[0] + r1[1] + r1[2] + r1[3];
        s2 = r2[0] + r2[1] + r2[2] + r2[3];
        const float mean = s1 * invM;
        const float var  = s2 * invM - mean * mean;
        const float rstd = rsqrtf(var + BNEPS);
        const float scale = gamma[oc] * rstd;
        stats[oc]     = scale;
        stats[C + oc] = beta[oc] - mean * scale;
    }
}

// ---------------------------------------------------------------------------
extern "C" void kernel_launch(void* const* d_in, const int* in_sizes, int n_in,
                              void* d_out, int out_size, void* d_ws, size_t ws_size,
                              hipStream_t stream)
{
    const float* x = (const float*)d_in[0];
    float* ws      = (float*)d_ws;
    float* S       = ws;                    //    262,144 f32 (S / S-partials)
    float* part    = S + 262144;            //  1,048,576 f32
    float* bnstats = part + 1048576;        //        512 f32
    _Float16* h      = (_Float16*)(bnstats + 512); // 16,777,216 f16
    _Float16* xnh    = h + 16777216;               //  4,194,304 f16
    _Float16* ratioh = xnh + 4194304;              //  4,194,304 f16
    _Float16* wA1h   = ratioh + 4194304;           //     73,728 f16
    _Float16* wB1h   = wA1h + 73728;               //     73,728 f16
    _Float16* wA2h   = wB1h + 73728;               //    294,912 f16
    _Float16* wB2h   = wA2h + 294912;              //    294,912 f16
    _Float16* w1h0   = wB2h + 294912;              //      4,096 f16
    _Float16* w1h1   = w1h0 + 4096;                //     16,384 f16
    _Float16* w1h2   = w1h1 + 16384;               //     65,536 f16
    _Float16* wA0h   = w1h2 + 65536;               //      9,216 f16
    _Float16* wB0h   = wA0h + 9216;                //      4,096 f16

    const int B = 16;

    prep_all_kernel<<<784, 256, 0, stream>>>(
        (const float*)d_in[1], (const float*)d_in[2],
        (const float*)d_in[6], (const float*)d_in[7],
        (const float*)d_in[11], (const float*)d_in[12],
        wA0h, wB0h, wA1h, wB1h, wA2h, wB2h, w1h0, w1h1, w1h2);

    // ---------------- Block 0: Cin=3, Cout=64, 128x128 ----------------
    {
        const int H = 128, W = 128, HW = H * W, npx = B * HW;
        xn0_kernel<<<npx / 256, 256, 0, stream>>>(x, xnh, npx, HW);
        mfconv5<64, 16, 1, 4, 4, 1, true, false, true>
            <<<dim3(8, 8, B), 256, 0, stream>>>(h, wA0h, xnh, ratioh, S, nullptr, H, W, npx);
        mf0u_kernel<true><<<dim3(8, 32, B), 256, 0, stream>>>(ratioh, wB0h, h, S, H, W);
        for (int it = 1; it < 5; ++it) {
            mfconv5<64, 16, 1, 4, 4, 1, true, false, false>
                <<<dim3(8, 8, B), 256, 0, stream>>>(h, wA0h, xnh, ratioh, S, nullptr, H, W, npx);
            mf0u_kernel<false><<<dim3(8, 32, B), 256, 0, stream>>>(ratioh, wB0h, h, S, H, W);
        }
        dim3 pg((W / 32) * (H / 2), B);
        posty_kernel<64, 0, 1><<<pg, 256, 0, stream>>>(h, S, w1h0, (const float*)d_in[3],
                                                       nullptr, part, nullptr, H, W, npx);
        stats_kernel<64><<<64, 256, 0, stream>>>(part, pg.x * pg.y, 1.0f / (float)npx,
                                                 (const float*)d_in[4], (const float*)d_in[5], bnstats);
        posty_kernel<64, 1, 1><<<pg, 256, 0, stream>>>(h, S, w1h0, (const float*)d_in[3],
                                                       bnstats, nullptr, xnh, H, W, npx);
    }

    // ---------------- Block 1: Cin=64, Cout=128, 64x64 ----------------
    {
        const int H = 64, W = 64, HW = H * W, npx = B * HW;
        mfconv5<128, 64, 1, 64, 64, 1, true, false, true>
            <<<dim3(4, 4, B), 256, 0, stream>>>(h, wA1h, xnh, ratioh, S, nullptr, H, W, npx);
        mfconv5<64, 128, 2, 128, 128, 1, false, true, true>
            <<<dim3(8, 4, B), 256, 0, stream>>>(ratioh, wB1h, nullptr, h, nullptr, S, H, W, npx);
        for (int it = 1; it < 5; ++it) {
            mfconv5<128, 64, 1, 64, 64, 2, true, false, false>
                <<<dim3(4, 4, B), 256, 0, stream>>>(h, wA1h, xnh, ratioh, S, nullptr, H, W, npx);
            mfconv5<64, 128, 2, 128, 128, 1, false, true, false>
                <<<dim3(8, 4, B), 256, 0, stream>>>(ratioh, wB1h, nullptr, h, nullptr, S, H, W, npx);
        }
        dim3 pg((W / 32) * (H / 2), B);
        posty_kernel<128, 0, 2><<<pg, 256, 0, stream>>>(h, S, w1h1, (const float*)d_in[8],
                                                        nullptr, part, nullptr, H, W, npx);
        stats_kernel<128><<<128, 256, 0, stream>>>(part, pg.x * pg.y, 1.0f / (float)npx,
                                                   (const float*)d_in[9], (const float*)d_in[10], bnstats);
        posty_kernel<128, 1, 2><<<pg, 256, 0, stream>>>(h, S, w1h1, (const float*)d_in[8],
                                                        bnstats, nullptr, xnh, H, W, npx);
    }

    // ---------------- Block 2: Cin=128, Cout=256, 32x32 ----------------
    {
        const int H = 32, W = 32, HW = H * W, npx = B * HW;
        mfconv5<256, 128, 4, 128, 128, 1, true, false, true>
            <<<dim3(8, 2, B), 256, 0, stream>>>(h, wA2h, xnh, ratioh, S, nullptr, H, W, npx);
        mfconv5<128, 256, 4, 256, 256, 1, false, true, true>
            <<<dim3(8, 2, B), 256, 0, stream>>>(ratioh, wB2h, nullptr, h, nullptr, S, H, W, npx);
        for (int it = 1; it < 5; ++it) {
            mfconv5<256, 128, 4, 128, 128, 4, true, false, false>
                <<<dim3(8, 2, B), 256, 0, stream>>>(h, wA2h, xnh, ratioh, S, nullptr, H, W, npx);
            mfconv5<128, 256, 4, 256, 256, 1, false, true, false>
                <<<dim3(8, 2, B), 256, 0, stream>>>(ratioh, wB2h, nullptr, h, nullptr, S, H, W, npx);
        }
        dim3 pg((W / 32) * (H / 2), B);
        posty_kernel<256, 0, 4><<<pg, 256, 0, stream>>>(h, S, w1h2, (const float*)d_in[13],
                                                        nullptr, part, nullptr, H, W, npx);
        stats_kernel<256><<<256, 256, 0, stream>>>(part, pg.x * pg.y, 1.0f / (float)npx,
                                                   (const float*)d_in[14], (const float*)d_in[15], bnstats);
        posty_kernel<256, 2, 4><<<pg, 256, 0, stream>>>(h, S, w1h2, (const float*)d_in[13],
                                                        bnstats, nullptr, d_out, H, W, npx);
    }
}